// Round 1
// 201.015 us; speedup vs baseline: 1.0001x; 1.0001x over previous
//
#include <hip/hip_runtime.h>

#define NTOK 32768
#define D 1024
#define NE 8
#define NWAVES 2048                  // 512 blocks * 4 waves
#define PAIR_STRIDE (2 * NWAVES)     // 4096 tokens per pair-iteration
#define NPAIRIT (NTOK / PAIR_STRIDE) // 8 iterations, no tail

// ---- cross-lane helpers ------------------------------------------------
// DPP row_ror rotate: lane gets value from (lane + k) within its 16-lane
// row. VALU pipe (free-ish) vs shfl (LDS pipe).
template<int CTRL>
__device__ __forceinline__ float dpp_ror(float v) {
    return __int_as_float(
        __builtin_amdgcn_update_dpp(0, __float_as_int(v), CTRL, 0xf, 0xf, true));
}

// sum over each 16-lane row (all lanes get row sum)
__device__ __forceinline__ float row_reduce_add(float v) {
    v += dpp_ror<0x121>(v);
    v += dpp_ror<0x122>(v);
    v += dpp_ror<0x124>(v);
    v += dpp_ror<0x128>(v);
    return v;
}

__device__ __forceinline__ float wave_reduce_add(float v) {
    v = row_reduce_add(v);
    v += __shfl_xor(v, 16, 64);
    v += __shfl_xor(v, 32, 64);
    return v;
}

// For period-8-replicated values: sum / max over the 8 distinct entries,
// entirely on the VALU (DPP) pipe. Valid because v(lane) depends only on
// lane&7, so row rotations by 1/2/4 hit the 8 distinct values exactly once.
__device__ __forceinline__ float grp8_add(float v) {
    v += dpp_ror<0x121>(v);
    v += dpp_ror<0x122>(v);
    v += dpp_ror<0x124>(v);
    return v;
}
__device__ __forceinline__ float grp8_max(float v) {
    v = fmaxf(v, dpp_ror<0x121>(v));
    v = fmaxf(v, dpp_ror<0x122>(v));
    v = fmaxf(v, dpp_ror<0x124>(v));
    return v;
}
// sum over lanes sharing (lane&7): ror:8 within a 16-row == xor 8
__device__ __forceinline__ float red_per_expert(float v) {
    v += dpp_ror<0x128>(v);
    v += __shfl_xor(v, 16, 64);
    v += __shfl_xor(v, 32, 64);
    return v;   // lane l holds sum over all 8 lanes with same (l&7)
}

// ---- kernel 1: fused logits + softmax + top-2 + stats ------------------
// Wave per TOKEN PAIR per iteration (R_polish: was 1 token/iter). Lane l
// owns d in {4l + 256c : c=0..3}; W stays resident in 128 VGPRs.
// Pairing doubles memory-level parallelism (8 KB in flight/wave) and gives
// 2x ILP across the long serial cross-lane chains (row_reduce -> select ->
// shfl -> softmax DPP -> ballots), which is what was latency-stretching
// each iteration at 2 waves/SIMD occupancy.
//
// REPLICATION NOTE: all 64 lanes of a wave process the SAME token, and the
// per-token quantities (p, counts) depend only on lane&7 — so per-expert
// accumulators are replicated 8x across the wave. red_per_expert sums the
// 8 copies; the final per-wave partials must be scaled by 1/8. (R2 bug:
// missing scale made load_balance_loss 64x too big — error 126. Entropy
// uses wave_reduce_add over 8 copies of the 8-expert sum -> -1/8 scale.)
__global__ __launch_bounds__(256, 2) void fused_kernel(
        const float* __restrict__ x, const float* __restrict__ W,
        float* __restrict__ logits, float* __restrict__ dw,
        float* __restrict__ eidx, float* __restrict__ ws) {
    const int lane = threadIdx.x & 63;
    const int wid  = (blockIdx.x * blockDim.x + threadIdx.x) >> 6;
    const int k    = lane & 7;

    float4 w[NE][4];
#pragma unroll
    for (int e = 0; e < NE; ++e)
#pragma unroll
        for (int c = 0; c < 4; ++c)
            w[e][c] = *(const float4*)(W + e * D + c * 256 + lane * 4);

    float p_acc = 0.f, c_acc = 0.f, ent_acc = 0.f;

    int t = wid * 2;                       // contiguous token pair (t, t+1)
    float4 xa[4], xb[4];
    {
        const float* xr = x + (size_t)t * D + lane * 4;
#pragma unroll
        for (int c = 0; c < 4; ++c) {
            xa[c] = *(const float4*)(xr + c * 256);
            xb[c] = *(const float4*)(xr + D + c * 256);
        }
    }

    for (int it = 0; it < NPAIRIT; ++it) {
        // software-prefetch next pair while computing current (uniform branch)
        float4 na[4], nb[4];
        if (it + 1 < NPAIRIT) {
            const float* xr = x + (size_t)(t + PAIR_STRIDE) * D + lane * 4;
#pragma unroll
            for (int c = 0; c < 4; ++c) {
                na[c] = *(const float4*)(xr + c * 256);
                nb[c] = *(const float4*)(xr + D + c * 256);
            }
        }

        // ---- dot products for both tokens: 16 independent FMA chains ----
        float accA[NE], accB[NE];
#pragma unroll
        for (int e = 0; e < NE; ++e) {
            float sa = 0.f, sb = 0.f;
#pragma unroll
            for (int c = 0; c < 4; ++c) {
                sa = fmaf(xa[c].x, w[e][c].x, sa);
                sb = fmaf(xb[c].x, w[e][c].x, sb);
                sa = fmaf(xa[c].y, w[e][c].y, sa);
                sb = fmaf(xb[c].y, w[e][c].y, sb);
                sa = fmaf(xa[c].z, w[e][c].z, sa);
                sb = fmaf(xb[c].z, w[e][c].z, sb);
                sa = fmaf(xa[c].w, w[e][c].w, sa);
                sb = fmaf(xb[c].w, w[e][c].w, sb);
            }
            accA[e] = sa; accB[e] = sb;
        }
        // 16 independent 4-deep DPP chains — scheduler interleaves freely
#pragma unroll
        for (int e = 0; e < NE; ++e) {
            accA[e] = row_reduce_add(accA[e]);
            accB[e] = row_reduce_add(accB[e]);
        }

        // ---- per-token softmax + top-2 (j fully unrolled -> static idx,
        //      two independent chains overlap) ----
        float vv[2], w1[2], w2[2], ee1[2], ee2[2];
#pragma unroll
        for (int j = 0; j < 2; ++j) {
            float a[NE];
#pragma unroll
            for (int e = 0; e < NE; ++e) a[e] = j ? accB[e] : accA[e];

            float b0 = (k & 1) ? a[1] : a[0];
            float b1 = (k & 1) ? a[3] : a[2];
            float b2 = (k & 1) ? a[5] : a[4];
            float b3 = (k & 1) ? a[7] : a[6];
            float c0 = (k & 2) ? b1 : b0;
            float c1 = (k & 2) ? b3 : b2;
            float v  = (k & 4) ? c1 : c0;
            v += __shfl_xor(v, 16, 64);
            v += __shfl_xor(v, 32, 64);   // v = logit[lane&7], replicated wave-wide

            // softmax over the 8 experts (all DPP, fully replicated)
            const float m    = grp8_max(v);
            const float pe   = __expf(v - m);
            const float S    = grp8_add(pe);
            const float p    = pe / S;
            const float logS = __logf(S);

            // top-2, lowest index wins ties
            const float m1 = grp8_max(p);
            const unsigned long long b1m = __ballot(p == m1);
            const int e1 = __ffsll(b1m & 0xffull) - 1;
            const float cand = (k == e1) ? -1.0f : p;
            const float m2 = grp8_max(cand);
            const unsigned long long b2m = __ballot(cand == m2);
            const int e2 = __ffsll(b2m & 0xffull) - 1;

            // stats (accumulate per-lane, reduce once per wave at end)
            p_acc   += p;
            c_acc   += (float)((k == e1) + (k == e2));
            ent_acc += p * (v - m - logS);   // = p * log p  (negative)

            vv[j] = v; w1[j] = m1; w2[j] = m2;
            ee1[j] = (float)e1; ee2[j] = (float)e2;
        }

        // ---- outputs: pair is contiguous -> wide stores ----
        // 16 contiguous logits (tokens t, t+1); lanes 8..15 hold token B's
        // replicated logits for expert lane&7.
        if (lane < 16)      logits[t * 8 + lane] = (lane < 8) ? vv[0] : vv[1];
        if (lane == 0)      *(float4*)(dw   + t * 2) = make_float4(w1[0],  w2[0],  w1[1],  w2[1]);
        else if (lane == 1) *(float4*)(eidx + t * 2) = make_float4(ee1[0], ee2[0], ee1[1], ee2[1]);

        t += PAIR_STRIDE;
#pragma unroll
        for (int c = 0; c < 4; ++c) { xa[c] = na[c]; xb[c] = nb[c]; }
    }

    // per-wave partials -> private ws slot. 0.125f undoes the 8x wave
    // replication (see REPLICATION NOTE above).
    const float pr = red_per_expert(p_acc) * 0.125f;  // lane l: expert l&7 prob sum
    const float cr = red_per_expert(c_acc) * 0.125f;  // lane l: expert l&7 count
    const float er = wave_reduce_add(ent_acc) * -0.125f;  // entropy sum
    const float outv = (lane < 8) ? pr : ((lane < 16) ? cr : er);
    if (lane < 17) ws[wid * 17 + lane] = outv;
}

// ---- kernel 2: reduce 2048x17 partials, emit scalars -------------------
// out tail: [0] load_balance_loss, [1] entropy_loss, [2] num_dropped,
// [3..10] expert_usage
__global__ __launch_bounds__(1024) void finalize_kernel(
        const float* __restrict__ ws, float* __restrict__ outs) {
    __shared__ float s_acc[17];
    const int tid = threadIdx.x;
    if (tid < 17) s_acc[tid] = 0.f;
    __syncthreads();

    float loc[17];
#pragma unroll
    for (int i = 0; i < 17; ++i) loc[i] = 0.f;
    for (int w = tid; w < NWAVES; w += 1024) {
        const float* p = ws + w * 17;
#pragma unroll
        for (int i = 0; i < 17; ++i) loc[i] += p[i];
    }
#pragma unroll
    for (int i = 0; i < 17; ++i) {
        const float r = wave_reduce_add(loc[i]);
        if ((tid & 63) == 0) atomicAdd(&s_acc[i], r);
    }
    __syncthreads();

    if (tid == 0) {
        const float invN = 1.0f / 32768.0f;
        float lbl = 0.f, dropped = 0.f;
#pragma unroll
        for (int e = 0; e < 8; ++e) {
            const float cnt = s_acc[8 + e];
            lbl += (cnt * invN) * (s_acc[e] * invN);
            if (cnt > 10240.0f) dropped += 1.f;    // capacity = 32768*2*1.25/8
            outs[3 + e] = cnt * invN;              // expert_usage
        }
        outs[0] = lbl * 8.0f;
        const float ent = s_acc[16] * invN;
        outs[1] = fmaxf(2.0794415416798357f - ent, 0.0f);   // log(8) - entropy
        outs[2] = dropped;
    }
}

extern "C" void kernel_launch(void* const* d_in, const int* in_sizes, int n_in,
                              void* d_out, int out_size, void* d_ws, size_t ws_size,
                              hipStream_t stream) {
    const float* x = (const float*)d_in[0];
    const float* W = (const float*)d_in[1];
    float* out     = (float*)d_out;

    // output layout (flat concat, everything fp32):
    float* dw      = out;            // [32768,2] dispatch_weights
    float* eidx    = out + 65536;    // [32768,2] expert_indices (as float)
    float* logits  = out + 131072;   // [32768,8] router_logits
    float* scalars = out + 393216;   // lbl, ent_loss, num_dropped, usage[8]
    float* ws      = (float*)d_ws;   // [2048,17] per-wave partials

    fused_kernel<<<512, 256, 0, stream>>>(x, W, logits, dw, eidx, ws);
    finalize_kernel<<<1, 1024, 0, stream>>>(ws, scalars);
}